// Round 1
// baseline (272.544 us; speedup 1.0000x reference)
//
#include <hip/hip_runtime.h>
#include <hip/hip_bf16.h>

// SkeletonLoss: out = sum_b mean_e ( ||p[b,s0]-p[b,s1]|| - init_len[e] )^2
// B=64, N=100000, E=200000.
// One thread per edge; each thread loops over a group of BATCH_GROUP batches
// (gridDim.y groups) so the int indices + init_len are loaded once per group.
// Per-batch point slice is 800 KB -> lives in L2; gathers are mostly L2 hits.

#define BATCH_GROUP 8

__global__ __launch_bounds__(256) void skeleton_loss_kernel(
    const float2* __restrict__ pts,      // [B*N] as float2
    const int*    __restrict__ skel,     // [E,2] int32
    const float*  __restrict__ init_len, // [E]
    float*        __restrict__ out,      // [1]
    int N, int E, float inv_E)
{
    int e = blockIdx.x * blockDim.x + threadIdx.x;
    float local = 0.0f;
    if (e < E) {
        int i0 = skel[2 * e];
        int i1 = skel[2 * e + 1];
        float l0 = init_len[e];
        int b0 = blockIdx.y * BATCH_GROUP;
        long base0 = (long)b0 * N;
        #pragma unroll
        for (int k = 0; k < BATCH_GROUP; ++k) {
            long base = base0 + (long)k * N;
            float2 p = pts[base + i0];
            float2 q = pts[base + i1];
            float dx = p.x - q.x;
            float dy = p.y - q.y;
            float len = sqrtf(dx * dx + dy * dy);
            float d = len - l0;
            local += d * d;
        }
    }

    // wave (64-lane) reduction
    #pragma unroll
    for (int off = 32; off > 0; off >>= 1)
        local += __shfl_down(local, off, 64);

    __shared__ float ws[4];
    int lane = threadIdx.x & 63;
    int wave = threadIdx.x >> 6;
    if (lane == 0) ws[wave] = local;
    __syncthreads();
    if (threadIdx.x == 0) {
        float s = (ws[0] + ws[1]) + (ws[2] + ws[3]);
        atomicAdd(out, s * inv_E);
    }
}

extern "C" void kernel_launch(void* const* d_in, const int* in_sizes, int n_in,
                              void* d_out, int out_size, void* d_ws, size_t ws_size,
                              hipStream_t stream) {
    const float2* pts      = (const float2*)d_in[0];  // [B,N,2] fp32
    const int*    skel     = (const int*)d_in[1];     // [E,2] int32
    const float*  init_len = (const float*)d_in[2];   // [E]
    float*        out      = (float*)d_out;

    const int B = 64;
    const int E = in_sizes[2];            // 200000
    const int N = in_sizes[0] / (B * 2);  // 100000

    // d_out is poisoned to 0xAA before every launch; zero it (stream-ordered,
    // graph-capture safe).
    hipMemsetAsync(out, 0, sizeof(float), stream);

    dim3 block(256);
    dim3 grid((E + 255) / 256, B / BATCH_GROUP);
    skeleton_loss_kernel<<<grid, block, 0, stream>>>(
        pts, skel, init_len, out, N, E, 1.0f / (float)E);
}

// Round 2
// 204.234 us; speedup vs baseline: 1.3345x; 1.3345x over previous
//
#include <hip/hip_runtime.h>
#include <hip/hip_bf16.h>

// SkeletonLoss: out = sum_b mean_e ( ||p[b,s0]-p[b,s1]|| - init_len[e] )^2
// B=64, N=100000, E=200000.
//
// R2: XCD-affine batch ownership. Blocks dispatch round-robin over the 8 XCDs
// (xcd ~ linear_block_id % 8). slot = blockIdx.x % 8 owns batches
// [slot*8, slot*8+8). All blocks of a slot live on one XCD and sweep those 8
// batches in the same order, so the per-XCD L2 (4 MB) only ever holds ~1-2
// point slices (800 KB each) -> each slice is fetched from HBM once, gathers
// hit L2. Edge indices + init_len are loaded once (int4/float4) and reused
// across the 8-batch register loop.

#define EDGES_PER_THREAD 4
#define BATCHES_PER_SLOT 8
#define BLOCK 256

__global__ __launch_bounds__(BLOCK) void skeleton_loss_kernel(
    const float2* __restrict__ pts,      // [B*N] as float2
    const int*    __restrict__ skel,     // [E,2] int32
    const float*  __restrict__ init_len, // [E]
    float*        __restrict__ out,      // [1]
    int N, int E, int blocksPerSlot, float inv_E)
{
    const int L    = blockIdx.x;
    const int slot = L & 7;            // XCD affinity (round-robin heuristic)
    const int j    = L >> 3;           // edge-chunk index within slot
    const int eBase = (j * BLOCK + threadIdx.x) * EDGES_PER_THREAD;

    int   i0[EDGES_PER_THREAD];
    int   i1[EDGES_PER_THREAD];
    float l0[EDGES_PER_THREAD];
    bool  valid[EDGES_PER_THREAD];

    if (eBase + EDGES_PER_THREAD <= E) {
        // vectorized: 4 consecutive edges -> 8 ints (2x int4) + 4 floats (float4)
        const int4* sk4 = (const int4*)(skel + 2 * eBase);
        int4 a = sk4[0];
        int4 b = sk4[1];
        float4 l4 = *(const float4*)(init_len + eBase);
        i0[0] = a.x; i1[0] = a.y; i0[1] = a.z; i1[1] = a.w;
        i0[2] = b.x; i1[2] = b.y; i0[3] = b.z; i1[3] = b.w;
        l0[0] = l4.x; l0[1] = l4.y; l0[2] = l4.z; l0[3] = l4.w;
        #pragma unroll
        for (int k = 0; k < EDGES_PER_THREAD; ++k) valid[k] = true;
    } else {
        #pragma unroll
        for (int k = 0; k < EDGES_PER_THREAD; ++k) {
            int e = eBase + k;
            valid[k] = (e < E);
            int ee = valid[k] ? e : 0;
            i0[k] = skel[2 * ee];
            i1[k] = skel[2 * ee + 1];
            l0[k] = init_len[ee];
        }
    }

    float acc = 0.0f;
    const int b0 = slot * BATCHES_PER_SLOT;
    for (int bb = 0; bb < BATCHES_PER_SLOT; ++bb) {
        const float2* p = pts + (size_t)(b0 + bb) * N;
        #pragma unroll
        for (int k = 0; k < EDGES_PER_THREAD; ++k) {
            float2 s = p[i0[k]];
            float2 d = p[i1[k]];
            float dx = s.x - d.x;
            float dy = s.y - d.y;
            float len = sqrtf(dx * dx + dy * dy);
            float df = len - l0[k];
            float v = df * df;
            if (valid[k]) acc += v;
        }
    }

    // wave (64-lane) reduction
    #pragma unroll
    for (int off = 32; off > 0; off >>= 1)
        acc += __shfl_down(acc, off, 64);

    __shared__ float ws[BLOCK / 64];
    int lane = threadIdx.x & 63;
    int wave = threadIdx.x >> 6;
    if (lane == 0) ws[wave] = acc;
    __syncthreads();
    if (threadIdx.x == 0) {
        float s = (ws[0] + ws[1]) + (ws[2] + ws[3]);
        atomicAdd(out, s * inv_E);
    }
}

extern "C" void kernel_launch(void* const* d_in, const int* in_sizes, int n_in,
                              void* d_out, int out_size, void* d_ws, size_t ws_size,
                              hipStream_t stream) {
    const float2* pts      = (const float2*)d_in[0];  // [B,N,2] fp32
    const int*    skel     = (const int*)d_in[1];     // [E,2] int32
    const float*  init_len = (const float*)d_in[2];   // [E]
    float*        out      = (float*)d_out;

    const int B = 64;
    const int E = in_sizes[2];            // 200000
    const int N = in_sizes[0] / (B * 2);  // 100000

    hipMemsetAsync(out, 0, sizeof(float), stream);

    const int edgesPerBlock = BLOCK * EDGES_PER_THREAD;            // 1024
    const int blocksPerSlot = (E + edgesPerBlock - 1) / edgesPerBlock; // 196
    dim3 block(BLOCK);
    dim3 grid(blocksPerSlot * 8);
    skeleton_loss_kernel<<<grid, block, 0, stream>>>(
        pts, skel, init_len, out, N, E, blocksPerSlot, 1.0f / (float)E);
}

// Round 3
// 142.871 us; speedup vs baseline: 1.9076x; 1.4295x over previous
//
#include <hip/hip_runtime.h>
#include <hip/hip_bf16.h>

// SkeletonLoss: out = sum_b mean_e ( ||p[b,s0]-p[b,s1]|| - init_len[e] )^2
// B=64, N=100000, E=200000.
//
// R3: random global gathers are MSHR-bound (~3.3 cyc/line-request/CU measured).
// Fix: tile-pair bucketing. Points split into T=10 tiles of P=10000 (80 KB).
// Edges bucketed on-device by canonical tile pair (55 live buckets of T*T=100).
// Persistent blocks (1/CU, 160 KB LDS = 2 tiles) stream tile pairs coalesced
// into LDS and evaluate each bucket's edges with LDS gathers. XCD-affine:
// block id % 8 = slot owns batches [slot*8, slot*8+8) so point slices stay in
// the local L2 and are fetched from HBM once.

#define T_TILES 10
#define PTILE   10000
#define NB2     (T_TILES * T_TILES)   // 100 buckets (upper-tri live)
#define MAIN_GRID 256
#define MAIN_BLOCK 1024

// ---- ws layout (bytes) ----
// [0,    1024)  cnt[256]
// [1024, 2052)  off[257]
// [2176, 3200)  cur[256]
// [4096, 4096+8E) recs int2[E]  {packed, bitcast(len)}
#define WS_CNT  0
#define WS_OFF  1024
#define WS_CUR  2176
#define WS_REC  4096

__device__ __forceinline__ void edge_bucket(int i0, int i1, int& bkt, unsigned& pk) {
    int ta = i0 / PTILE, tb = i1 / PTILE;
    int a = min(ta, tb), b = max(ta, tb);
    bkt = a * T_TILES + b;
    unsigned o0 = (unsigned)(i0 - ta * PTILE);
    unsigned o1 = (unsigned)(i1 - tb * PTILE);
    unsigned s0 = (ta != a) ? 1u : 0u;
    unsigned s1 = (tb != a) ? 1u : 0u;
    pk = o0 | (s0 << 15) | (o1 << 16) | (s1 << 31);
}

__global__ __launch_bounds__(1024) void hist_kernel(
    const int2* __restrict__ skel, int* __restrict__ cnt, int E)
{
    __shared__ int h[256];
    if (threadIdx.x < 256) h[threadIdx.x] = 0;
    __syncthreads();
    int e = blockIdx.x * blockDim.x + threadIdx.x;
    if (e < E) {
        int2 s = skel[e];
        int bkt; unsigned pk;
        edge_bucket(s.x, s.y, bkt, pk);
        atomicAdd(&h[bkt], 1);
    }
    __syncthreads();
    if (threadIdx.x < 256 && h[threadIdx.x])
        atomicAdd(&cnt[threadIdx.x], h[threadIdx.x]);
}

__global__ __launch_bounds__(256) void scan_kernel(
    const int* __restrict__ cnt, int* __restrict__ off, int* __restrict__ cur)
{
    __shared__ int s[256];
    int t = threadIdx.x;
    int v = cnt[t];   // bins >= NB2 are zero (memset)
    s[t] = v;
    __syncthreads();
    #pragma unroll
    for (int d = 1; d < 256; d <<= 1) {
        int x = (t >= d) ? s[t - d] : 0;
        __syncthreads();
        s[t] += x;
        __syncthreads();
    }
    int ex = s[t] - v;                 // exclusive prefix
    if (t <= NB2) off[t] = ex + ((t == NB2) ? v : 0) - ((t == NB2) ? v : 0);
    if (t <= NB2) off[t] = ex;         // off[NB2] = total of first NB2 bins = E
    if (t < NB2) cur[t] = ex;
}

__global__ __launch_bounds__(1024) void scatter_kernel(
    const int2* __restrict__ skel, const float* __restrict__ init_len,
    int* __restrict__ cur, int2* __restrict__ recs, int E)
{
    __shared__ int h[256];
    __shared__ int base[256];
    if (threadIdx.x < 256) h[threadIdx.x] = 0;
    __syncthreads();
    int e = blockIdx.x * blockDim.x + threadIdx.x;
    int bkt = 0, lrank = 0; unsigned pk = 0;
    if (e < E) {
        int2 s = skel[e];
        edge_bucket(s.x, s.y, bkt, pk);
        lrank = atomicAdd(&h[bkt], 1);
    }
    __syncthreads();
    if (threadIdx.x < 256 && h[threadIdx.x])
        base[threadIdx.x] = atomicAdd(&cur[threadIdx.x], h[threadIdx.x]);
    __syncthreads();
    if (e < E) {
        int pos = base[bkt] + lrank;
        recs[pos] = make_int2((int)pk, __float_as_int(init_len[e]));
    }
}

__global__ __launch_bounds__(MAIN_BLOCK) void skeleton_main_kernel(
    const float2* __restrict__ pts, const int2* __restrict__ recs,
    const int* __restrict__ off, float* __restrict__ out,
    int N, float inv_E)
{
    __shared__ float2 tileA[PTILE];
    __shared__ float2 tileB[PTILE];
    __shared__ float wsum[MAIN_BLOCK / 64];

    const int l = blockIdx.x;
    const int slot = l & 7;     // XCD affinity; owns batches [slot*8, slot*8+8)
    const int c = l >> 3;       // 0..31 within slot

    float acc = 0.0f;

    for (int w = c; w < 8 * NB2; w += 32) {
        int q = w / NB2;               // batch within slot
        int p = w - q * NB2;           // bucket id
        int a = p / T_TILES;
        int b = p - a * T_TILES;
        if (a > b) continue;           // uniform across block
        int lo = off[p], hi = off[p + 1];
        if (lo == hi) continue;
        int batch = slot * 8 + q;

        __syncthreads();   // previous item's readers done before overwrite

        // stream tile a -> tileA (coalesced float4)
        {
            const size_t baseg = (size_t)batch * N + (size_t)a * PTILE;
            int pc = min(PTILE, N - a * PTILE);
            const float4* g4 = (const float4*)(pts + baseg);
            float4* d4 = (float4*)tileA;
            int nch = (pc + 1) >> 1;
            for (int cc = threadIdx.x; cc < nch; cc += MAIN_BLOCK) d4[cc] = g4[cc];
        }
        if (b != a) {
            const size_t baseg = (size_t)batch * N + (size_t)b * PTILE;
            int pc = min(PTILE, N - b * PTILE);
            const float4* g4 = (const float4*)(pts + baseg);
            float4* d4 = (float4*)tileB;
            int nch = (pc + 1) >> 1;
            for (int cc = threadIdx.x; cc < nch; cc += MAIN_BLOCK) d4[cc] = g4[cc];
        }
        __syncthreads();

        for (int e = lo + (int)threadIdx.x; e < hi; e += MAIN_BLOCK) {
            int2 r = recs[e];
            unsigned pk = (unsigned)r.x;
            float l0 = __int_as_float(r.y);
            int o0 = pk & 0x7fff;
            int s0 = (pk >> 15) & 1;
            int o1 = (pk >> 16) & 0x7fff;
            int s1 = (int)(pk >> 31);
            const float2* t0 = s0 ? tileB : tileA;
            const float2* t1 = s1 ? tileB : tileA;
            float2 P0 = t0[o0];
            float2 P1 = t1[o1];
            float dx = P0.x - P1.x;
            float dy = P0.y - P1.y;
            float len = sqrtf(dx * dx + dy * dy);
            float d = len - l0;
            acc += d * d;
        }
    }

    // block reduction
    #pragma unroll
    for (int offx = 32; offx > 0; offx >>= 1)
        acc += __shfl_down(acc, offx, 64);
    int lane = threadIdx.x & 63;
    int wave = threadIdx.x >> 6;
    if (lane == 0) wsum[wave] = acc;
    __syncthreads();
    if (wave == 0) {
        float v = (lane < MAIN_BLOCK / 64) ? wsum[lane] : 0.0f;
        #pragma unroll
        for (int offx = 8; offx > 0; offx >>= 1)
            v += __shfl_down(v, offx, 64);
        if (lane == 0) atomicAdd(out, v * inv_E);
    }
}

// ---------- fallback (R2 style) if ws too small or shape unexpected ----------
__global__ __launch_bounds__(256) void skeleton_loss_fallback(
    const float2* __restrict__ pts, const int* __restrict__ skel,
    const float* __restrict__ init_len, float* __restrict__ out,
    int N, int E, float inv_E)
{
    const int L = blockIdx.x;
    const int slot = L & 7;
    const int j = L >> 3;
    int e = j * 256 + threadIdx.x;
    float acc = 0.0f;
    if (e < E) {
        int i0 = skel[2 * e], i1 = skel[2 * e + 1];
        float l0 = init_len[e];
        for (int bb = 0; bb < 8; ++bb) {
            const float2* p = pts + (size_t)(slot * 8 + bb) * N;
            float2 s = p[i0], d = p[i1];
            float dx = s.x - d.x, dy = s.y - d.y;
            float len = sqrtf(dx * dx + dy * dy);
            float df = len - l0;
            acc += df * df;
        }
    }
    #pragma unroll
    for (int offx = 32; offx > 0; offx >>= 1)
        acc += __shfl_down(acc, offx, 64);
    __shared__ float ws[4];
    if ((threadIdx.x & 63) == 0) ws[threadIdx.x >> 6] = acc;
    __syncthreads();
    if (threadIdx.x == 0)
        atomicAdd(out, (ws[0] + ws[1] + ws[2] + ws[3]) * inv_E);
}

extern "C" void kernel_launch(void* const* d_in, const int* in_sizes, int n_in,
                              void* d_out, int out_size, void* d_ws, size_t ws_size,
                              hipStream_t stream) {
    const float2* pts      = (const float2*)d_in[0];
    const int*    skel     = (const int*)d_in[1];
    const float*  init_len = (const float*)d_in[2];
    float*        out      = (float*)d_out;

    const int B = 64;
    const int E = in_sizes[2];
    const int N = in_sizes[0] / (B * 2);
    const float inv_E = 1.0f / (float)E;

    hipMemsetAsync(out, 0, sizeof(float), stream);

    const size_t ws_need = (size_t)WS_REC + (size_t)E * 8;
    const bool ok = (ws_size >= ws_need) &&
                    (N <= T_TILES * PTILE) && (N > (T_TILES - 1) * PTILE) &&
                    ((N & 1) == 0);

    if (!ok) {
        dim3 grid(((E + 255) / 256) * 8);
        skeleton_loss_fallback<<<grid, 256, 0, stream>>>(
            pts, skel, init_len, out, N, E, inv_E);
        return;
    }

    char* ws = (char*)d_ws;
    int* cnt  = (int*)(ws + WS_CNT);
    int* off  = (int*)(ws + WS_OFF);
    int* cur  = (int*)(ws + WS_CUR);
    int2* recs = (int2*)(ws + WS_REC);

    hipMemsetAsync(cnt, 0, 1024, stream);

    int nblk = (E + 1023) / 1024;
    hist_kernel<<<nblk, 1024, 0, stream>>>((const int2*)skel, cnt, E);
    scan_kernel<<<1, 256, 0, stream>>>(cnt, off, cur);
    scatter_kernel<<<nblk, 1024, 0, stream>>>((const int2*)skel, init_len, cur, recs, E);
    skeleton_main_kernel<<<MAIN_GRID, MAIN_BLOCK, 0, stream>>>(
        pts, recs, off, out, N, inv_E);
}